// Round 15
// baseline (71.976 us; speedup 1.0000x reference)
//
#include <hip/hip_runtime.h>
#include <hip/hip_bf16.h>

// Problem constants (fixed by the bench): B=2, Tq=Tv=2048, D=512, H=8, dh=64.
// Inputs and output are FLOAT32.
#define BATCH 2
#define TSEQ  2048
#define DMODEL 512
#define NHEAD 8
#define DHEAD 64

typedef __bf16 bf16x2 __attribute__((ext_vector_type(2)));
typedef __bf16 bf16x4 __attribute__((ext_vector_type(4)));
typedef __bf16 bf16x8 __attribute__((ext_vector_type(8)));
typedef float  f32x4  __attribute__((ext_vector_type(4)));

#if __has_builtin(__builtin_amdgcn_exp2f)
#define EXP2(x) __builtin_amdgcn_exp2f(x)   // raw v_exp_f32 (exp2f links ocml)
#else
#define EXP2(x) exp2f(x)
#endif

__device__ __forceinline__ bf16x8 load_b8(const void* p) {
  return __builtin_bit_cast(bf16x8, *reinterpret_cast<const uint4*>(p));
}

// load 8 fp32 and convert to bf16x8 (p must be 16B-aligned)
__device__ __forceinline__ bf16x8 cvt8(const float* p) {
  float4 a = *reinterpret_cast<const float4*>(p);
  float4 b = *reinterpret_cast<const float4*>(p + 4);
  bf16x8 r;
  r[0] = (__bf16)a.x; r[1] = (__bf16)a.y; r[2] = (__bf16)a.z; r[3] = (__bf16)a.w;
  r[4] = (__bf16)b.x; r[5] = (__bf16)b.y; r[6] = (__bf16)b.z; r[7] = (__bf16)b.w;
  return r;
}

// load 8 fp32, scale, convert to bf16x8
__device__ __forceinline__ bf16x8 cvt8s(const float* p, float s) {
  float4 a = *reinterpret_cast<const float4*>(p);
  float4 b = *reinterpret_cast<const float4*>(p + 4);
  bf16x8 r;
  r[0] = (__bf16)(a.x * s); r[1] = (__bf16)(a.y * s);
  r[2] = (__bf16)(a.z * s); r[3] = (__bf16)(a.w * s);
  r[4] = (__bf16)(b.x * s); r[5] = (__bf16)(b.y * s);
  r[6] = (__bf16)(b.z * s); r[7] = (__bf16)(b.w * s);
  return r;
}

// pack two f32 to bf16 pair by truncation
__device__ __forceinline__ uint packbf(float a, float b) {
  uint ua = __builtin_bit_cast(uint, a);
  uint ub = __builtin_bit_cast(uint, b);
  return (ua >> 16) | (ub & 0xFFFF0000u);
}

// Tiled K layout: Kt[b][tset(128)][h(8)][g(2)][lane(64)][8elem]  (4 MiB)
#define KT_B   1048576
#define KT_T   8192
// Tiled V layout: Vtile[b][kset32(64)][dt(4)][lane(64)][8elem]   (512 KiB)
#define VT_B   131072
#define VT_K   2048

// ---------------------------------------------------------------------------
// Kernel 1: conv1d(k=1): Kt = bf16( V @ W^T + bias ) in tiled layout.
// ---------------------------------------------------------------------------
__global__ __launch_bounds__(256) void conv_kernel(
    const float* __restrict__ V,
    const float* __restrict__ W,
    const float* __restrict__ bias,
    __hip_bfloat16* __restrict__ Kt) {
  const int bx = blockIdx.x;
  const int b    = bx >> 7;
  const int tset = bx & 127;
  const int t0   = tset << 4;
  const int w  = threadIdx.x >> 6;
  const int l  = threadIdx.x & 63;
  const int lm = l & 15;
  const int lg = l >> 4;

  const float* vrow = V + ((size_t)(b * TSEQ + t0 + lm)) * DHEAD;
  bf16x8 av0 = cvt8(vrow + lg * 8);
  bf16x8 av1 = cvt8(vrow + 32 + lg * 8);

  #pragma unroll
  for (int n = 0; n < 8; ++n) {
    const int o0 = (w * 8 + n) * 16;
    const float* wrow = W + ((size_t)(o0 + lm)) * DHEAD;
    bf16x8 b0 = cvt8(wrow + lg * 8);
    bf16x8 b1 = cvt8(wrow + 32 + lg * 8);
    f32x4 acc = {0.f, 0.f, 0.f, 0.f};
    acc = __builtin_amdgcn_mfma_f32_16x16x32_bf16(av0, b0, acc, 0, 0, 0);
    acc = __builtin_amdgcn_mfma_f32_16x16x32_bf16(av1, b1, acc, 0, 0, 0);
    const int o   = o0 + lm;
    const int h   = o >> 6;
    const int gg  = (o >> 5) & 1;
    const int lgt = (o >> 3) & 3;
    const int j   = o & 7;
    const float bv = bias[o];
    const size_t kbase = (size_t)b * KT_B + (size_t)tset * KT_T +
                         h * 1024 + gg * 512 + lgt * 128 + j;
    #pragma unroll
    for (int r = 0; r < 4; ++r)
      Kt[kbase + (size_t)(lg * 4 + r) * 8] = __float2bfloat16(acc[r] + bv);
  }
}

// ---------------------------------------------------------------------------
// Kernel 2: Vtile from V via LDS tile transpose.
// ---------------------------------------------------------------------------
__global__ __launch_bounds__(256) void vt_kernel(const float* __restrict__ V,
                                                 __hip_bfloat16* __restrict__ Vtile) {
  const int bx = blockIdx.x;
  const int b  = bx >> 5;
  const int t0 = (bx & 31) << 6;
  const int tid = threadIdx.x;
  __shared__ float tile[64][65];

  #pragma unroll
  for (int p = 0; p < 4; ++p) {
    const int r = p * 16 + (tid >> 4);
    const int c = (tid & 15) * 4;
    float4 v = *reinterpret_cast<const float4*>(
        &V[((size_t)(b * TSEQ + t0 + r)) * DHEAD + c]);
    tile[r][c]     = v.x;
    tile[r][c + 1] = v.y;
    tile[r][c + 2] = v.z;
    tile[r][c + 3] = v.w;
  }
  __syncthreads();

  const int dt = tid >> 6;
  const int l  = tid & 63;
  const int lm = l & 15;
  const int lg = l >> 4;
  #pragma unroll
  for (int ks2 = 0; ks2 < 2; ++ks2) {
    bf16x8 o;
    #pragma unroll
    for (int jj = 0; jj < 4; ++jj) {
      o[jj]     = (__bf16)tile[ks2 * 32 + lg * 4 + jj][dt * 16 + lm];
      o[jj + 4] = (__bf16)tile[ks2 * 32 + 16 + lg * 4 + jj][dt * 16 + lm];
    }
    *reinterpret_cast<uint4*>(
        Vtile + (size_t)b * VT_B + (size_t)((t0 >> 5) + ks2) * VT_K +
        dt * 512 + l * 8) = __builtin_bit_cast(uint4, o);
  }
}

// ---------------------------------------------------------------------------
// Kernel 3 (R15): single-pass 8-wave cooperative attention, no k-split.
// 256 blocks (1/CU, XCD-swizzled) x 512 threads (8 waves, 2/SIMD).
// R14 lesson: per-wave total regs (VGPR+AGPR) ~140 fits the 128-VGPR cap
// that 512-thread blocks get -> no spill, and 8 waves/CU from one block.
// Per 256-k round:
//   S-phase : wave w owns kset32 s=w (tsets R*16+2w,+1): QK^T via
//             mfma(K,Q) (S^T lane-local), heads-softmax (op-diet), weights
//             -> Ws[w][h] in B-frag layout (conflict-free 1KB writes).
//   PV-phase: wave w owns (d-quadrant w&3, heads [4*(w>>2),+4)): reads all
//             8 strips' Ws, accO[4 heads] only 16 regs. No cross-wave
//             reduction, no partials, no reduce kernel.
// Qs is stored in Kt-style tiled layout -> all LDS fragment reads/writes are
// contiguous 1KB per (h,g) = bank-conflict-free (R14's 2.56M conflicts were
// the XOR-swizzled row-major Qs: 1KB row stride aliases all 32 banks).
// V loads issue at round top, consumed after S-phase (~1500cy later).
// ---------------------------------------------------------------------------
__global__ __launch_bounds__(512, 1) void attn_kernel(
    const float* __restrict__ Q,
    const __hip_bfloat16* __restrict__ Kt,
    const __hip_bfloat16* __restrict__ Vtile,
    float* __restrict__ Out) {
  const int bx = blockIdx.x;
  const int L  = (bx & 7) * 32 + (bx >> 3);
  const int b  = L >> 7;
  const int q0 = (L & 127) << 4;
  const int tid = threadIdx.x;
  const int w   = tid >> 6;           // 0..7
  const int l   = tid & 63;
  const int lm  = l & 15;
  const int lg  = l >> 4;
  const int myh0 = (w >> 2) * 4;      // this wave's head-half base
  const int mydt = w & 3;             // this wave's d-quadrant

  __shared__ __bf16 Qs[8192];         // tiled [hg(16)][lane(64)][8], 16 KiB
  __shared__ __bf16 Ws[8][NHEAD][512];// [strip][h][frag], 64 KiB
  __shared__ float  Obuf[2][64][17];  // per-head-group epilogue transpose

  // ---- stage Q to LDS in tiled layout (pre-scaled by dh^-0.5*log2e) ----
  const float cl2 = 0.125f * 1.44269504f;
  {
    const int hg = tid >> 5;          // 0..15  (h = hg>>1, g = hg&1)
    const int wi = tid & 31;
    const int h = hg >> 1, g = hg & 1;
    #pragma unroll
    for (int u = 0; u < 2; ++u) {
      const int ll  = u * 32 + wi;    // dest lane 0..63
      const int row = ll & 15;
      const int seg = ll >> 4;        // 0..3
      const float* src = Q + ((size_t)(b * TSEQ + q0 + row)) * DMODEL +
                         h * DHEAD + g * 32 + seg * 8;
      bf16x8 v = cvt8s(src, cl2);
      *(bf16x8*)((char*)Qs + hg * 1024 + ll * 16) = v;
    }
  }
  __syncthreads();

  f32x4 accO[4];        // heads myh0..myh0+3; q = lm, d = mydt*16 + lg*4 + r
  #pragma unroll
  for (int hh = 0; hh < 4; ++hh) accO[hh] = (f32x4){0.f, 0.f, 0.f, 0.f};

  #define S_HALF(TSET, S2)                                                    \
    {                                                                         \
      const __hip_bfloat16* kb_ =                                             \
          Kt + (size_t)b * KT_B + (size_t)(TSET) * KT_T + l * 8;              \
      f32x4 sv[NHEAD];                                                        \
      __builtin_amdgcn_s_setprio(1);                                          \
      _Pragma("unroll")                                                       \
      for (int h = 0; h < NHEAD; ++h) {                                       \
        bf16x8 kf0 = load_b8(kb_ + h * 1024);                                 \
        bf16x8 kf1 = load_b8(kb_ + h * 1024 + 512);                           \
        bf16x8 q0_ = *(const bf16x8*)((const char*)Qs + (h * 2) * 1024 + l * 16);     \
        bf16x8 q1_ = *(const bf16x8*)((const char*)Qs + (h * 2 + 1) * 1024 + l * 16); \
        f32x4 t = {0.f, 0.f, 0.f, 0.f};                                       \
        t = __builtin_amdgcn_mfma_f32_16x16x32_bf16(kf0, q0_, t, 0, 0, 0);    \
        t = __builtin_amdgcn_mfma_f32_16x16x32_bf16(kf1, q1_, t, 0, 0, 0);    \
        sv[h] = t;                                                            \
      }                                                                       \
      __builtin_amdgcn_s_setprio(0);                                          \
      _Pragma("unroll")                                                       \
      for (int rp = 0; rp < 2; ++rp) {                                        \
        float w0_[NHEAD], w1_[NHEAD];                                         \
        float s0_ = 0.f, s1_ = 0.f;                                           \
        _Pragma("unroll")                                                     \
        for (int h = 0; h < NHEAD; ++h) { w0_[h] = EXP2(sv[h][2 * rp]);     s0_ += w0_[h]; } \
        _Pragma("unroll")                                                     \
        for (int h = 0; h < NHEAD; ++h) { w1_[h] = EXP2(sv[h][2 * rp + 1]); s1_ += w1_[h]; } \
        const float i0_ = __builtin_amdgcn_rcpf(s0_);                         \
        const float i1_ = __builtin_amdgcn_rcpf(s1_);                         \
        _Pragma("unroll")                                                     \
        for (int h = 0; h < NHEAD; ++h)                                       \
          wfu[h][(S2) * 2 + rp] = packbf(w0_[h] * i0_, w1_[h] * i1_);         \
      }                                                                       \
    }

  #pragma unroll 1
  for (int R = 0; R < 8; ++R) {
    // ---- issue-early V for THIS round (consumed after S + barrier) ----
    bf16x8 vc[8];
    {
      const __hip_bfloat16* vb_ = Vtile + (size_t)b * VT_B +
          (size_t)(R * 8) * VT_K + mydt * 512 + l * 8;
      #pragma unroll
      for (int s = 0; s < 8; ++s) vc[s] = load_b8(vb_ + s * VT_K);
    }

    // ---- S phase: this wave's 32-k strip, all heads ----
    uint wfu[NHEAD][4];
    const int ts0 = R * 16 + w * 2;
    S_HALF(ts0, 0);
    S_HALF(ts0 + 1, 1);
    #pragma unroll
    for (int h = 0; h < NHEAD; ++h)
      *reinterpret_cast<uint4*>((char*)(&Ws[w][h][0]) + l * 16) =
          uint4{wfu[h][0], wfu[h][1], wfu[h][2], wfu[h][3]};
    __syncthreads();

    // ---- PV phase: all 8 strips, my 4 heads, my d-quadrant ----
    __builtin_amdgcn_s_setprio(1);
    #pragma unroll
    for (int s = 0; s < 8; ++s) {
      #pragma unroll
      for (int hh = 0; hh < 4; ++hh) {
        bf16x8 wsf = *(const bf16x8*)((const char*)(&Ws[s][myh0 + hh][0]) + l * 16);
        accO[hh] = __builtin_amdgcn_mfma_f32_16x16x32_bf16(vc[s], wsf, accO[hh], 0, 0, 0);
      }
    }
    __builtin_amdgcn_s_setprio(0);
    __syncthreads();
  }

  #undef S_HALF

  // ---- epilogue: 4 rounds; head-groups 0/1 write heads in parallel ----
  float* obase = Out + ((size_t)(b * TSEQ + q0)) * DMODEL;
  #pragma unroll
  for (int hh = 0; hh < 4; ++hh) {
    #pragma unroll
    for (int r = 0; r < 4; ++r)
      Obuf[w >> 2][mydt * 16 + lg * 4 + r][lm] = accO[hh][r];
    __syncthreads();
    {
      const int gg = tid >> 8;          // 0..1 head group
      const int wi = tid & 255;
      const int q  = wi >> 4;           // 0..15
      const int d0 = (wi & 15) * 4;     // 0..60
      const int h  = gg * 4 + hh;
      float4 s = {Obuf[gg][d0][q], Obuf[gg][d0 + 1][q],
                  Obuf[gg][d0 + 2][q], Obuf[gg][d0 + 3][q]};
      *reinterpret_cast<float4*>(&obase[(size_t)q * DMODEL + h * DHEAD + d0]) = s;
    }
    __syncthreads();
  }
}

// ---------------------------------------------------------------------------
extern "C" void kernel_launch(void* const* d_in, const int* in_sizes, int n_in,
                              void* d_out, int out_size, void* d_ws, size_t ws_size,
                              hipStream_t stream) {
  const float* Q    = (const float*)d_in[0];
  const float* V    = (const float*)d_in[1];
  const float* W    = (const float*)d_in[2];
  const float* bias = (const float*)d_in[3];
  float* Out = (float*)d_out;

  // ws layout: Kt bf16 4MiB | Vtile bf16 512KiB
  __hip_bfloat16* Ktb = (__hip_bfloat16*)d_ws;
  __hip_bfloat16* Vtb = Ktb + (size_t)BATCH * KT_B;

  conv_kernel<<<256, 256, 0, stream>>>(V, W, bias, Ktb);
  vt_kernel<<<64, 256, 0, stream>>>(V, Vtb);
  attn_kernel<<<BATCH * (TSEQ / 16), 512, 0, stream>>>(Q, Ktb, Vtb, Out);
}

// Round 16
// 53.082 us; speedup vs baseline: 1.3559x; 1.3559x over previous
//
#include <hip/hip_runtime.h>
#include <hip/hip_bf16.h>

// Problem constants (fixed by the bench): B=2, Tq=Tv=2048, D=512, H=8, dh=64.
// Inputs and output are FLOAT32.
#define BATCH 2
#define TSEQ  2048
#define DMODEL 512
#define NHEAD 8
#define DHEAD 64

typedef __bf16 bf16x2 __attribute__((ext_vector_type(2)));
typedef __bf16 bf16x4 __attribute__((ext_vector_type(4)));
typedef __bf16 bf16x8 __attribute__((ext_vector_type(8)));
typedef float  f32x4  __attribute__((ext_vector_type(4)));

#if __has_builtin(__builtin_amdgcn_exp2f)
#define EXP2(x) __builtin_amdgcn_exp2f(x)   // raw v_exp_f32 (exp2f links ocml)
#else
#define EXP2(x) exp2f(x)
#endif

__device__ __forceinline__ bf16x8 load_b8(const void* p) {
  return __builtin_bit_cast(bf16x8, *reinterpret_cast<const uint4*>(p));
}

// load 8 fp32 and convert to bf16x8 (p must be 16B-aligned)
__device__ __forceinline__ bf16x8 cvt8(const float* p) {
  float4 a = *reinterpret_cast<const float4*>(p);
  float4 b = *reinterpret_cast<const float4*>(p + 4);
  bf16x8 r;
  r[0] = (__bf16)a.x; r[1] = (__bf16)a.y; r[2] = (__bf16)a.z; r[3] = (__bf16)a.w;
  r[4] = (__bf16)b.x; r[5] = (__bf16)b.y; r[6] = (__bf16)b.z; r[7] = (__bf16)b.w;
  return r;
}

// load 8 fp32, scale, convert to bf16x8
__device__ __forceinline__ bf16x8 cvt8s(const float* p, float s) {
  float4 a = *reinterpret_cast<const float4*>(p);
  float4 b = *reinterpret_cast<const float4*>(p + 4);
  bf16x8 r;
  r[0] = (__bf16)(a.x * s); r[1] = (__bf16)(a.y * s);
  r[2] = (__bf16)(a.z * s); r[3] = (__bf16)(a.w * s);
  r[4] = (__bf16)(b.x * s); r[5] = (__bf16)(b.y * s);
  r[6] = (__bf16)(b.z * s); r[7] = (__bf16)(b.w * s);
  return r;
}

// pack two f32 to bf16 pair by truncation
__device__ __forceinline__ uint packbf(float a, float b) {
  uint ua = __builtin_bit_cast(uint, a);
  uint ub = __builtin_bit_cast(uint, b);
  return (ua >> 16) | (ub & 0xFFFF0000u);
}

// Tiled K layout: Kt[b][tset(128)][h(8)][g(2)][lane(64)][8elem]  (4 MiB)
#define KT_B   1048576
#define KT_T   8192
// Tiled V layout: Vtile[b][kset32(64)][dt(4)][lane(64)][8elem]   (512 KiB)
#define VT_B   131072
#define VT_K   2048

// ---------------------------------------------------------------------------
// Kernel 1: conv1d(k=1): Kt = bf16( V @ W^T + bias ) in tiled layout.
// ---------------------------------------------------------------------------
__global__ __launch_bounds__(256) void conv_kernel(
    const float* __restrict__ V,
    const float* __restrict__ W,
    const float* __restrict__ bias,
    __hip_bfloat16* __restrict__ Kt) {
  const int bx = blockIdx.x;
  const int b    = bx >> 7;
  const int tset = bx & 127;
  const int t0   = tset << 4;
  const int w  = threadIdx.x >> 6;
  const int l  = threadIdx.x & 63;
  const int lm = l & 15;
  const int lg = l >> 4;

  const float* vrow = V + ((size_t)(b * TSEQ + t0 + lm)) * DHEAD;
  bf16x8 av0 = cvt8(vrow + lg * 8);
  bf16x8 av1 = cvt8(vrow + 32 + lg * 8);

  #pragma unroll
  for (int n = 0; n < 8; ++n) {
    const int o0 = (w * 8 + n) * 16;
    const float* wrow = W + ((size_t)(o0 + lm)) * DHEAD;
    bf16x8 b0 = cvt8(wrow + lg * 8);
    bf16x8 b1 = cvt8(wrow + 32 + lg * 8);
    f32x4 acc = {0.f, 0.f, 0.f, 0.f};
    acc = __builtin_amdgcn_mfma_f32_16x16x32_bf16(av0, b0, acc, 0, 0, 0);
    acc = __builtin_amdgcn_mfma_f32_16x16x32_bf16(av1, b1, acc, 0, 0, 0);
    const int o   = o0 + lm;
    const int h   = o >> 6;
    const int gg  = (o >> 5) & 1;
    const int lgt = (o >> 3) & 3;
    const int j   = o & 7;
    const float bv = bias[o];
    const size_t kbase = (size_t)b * KT_B + (size_t)tset * KT_T +
                         h * 1024 + gg * 512 + lgt * 128 + j;
    #pragma unroll
    for (int r = 0; r < 4; ++r)
      Kt[kbase + (size_t)(lg * 4 + r) * 8] = __float2bfloat16(acc[r] + bv);
  }
}

// ---------------------------------------------------------------------------
// Kernel 2: Vtile from V via LDS tile transpose.
// ---------------------------------------------------------------------------
__global__ __launch_bounds__(256) void vt_kernel(const float* __restrict__ V,
                                                 __hip_bfloat16* __restrict__ Vtile) {
  const int bx = blockIdx.x;
  const int b  = bx >> 5;
  const int t0 = (bx & 31) << 6;
  const int tid = threadIdx.x;
  __shared__ float tile[64][65];

  #pragma unroll
  for (int p = 0; p < 4; ++p) {
    const int r = p * 16 + (tid >> 4);
    const int c = (tid & 15) * 4;
    float4 v = *reinterpret_cast<const float4*>(
        &V[((size_t)(b * TSEQ + t0 + r)) * DHEAD + c]);
    tile[r][c]     = v.x;
    tile[r][c + 1] = v.y;
    tile[r][c + 2] = v.z;
    tile[r][c + 3] = v.w;
  }
  __syncthreads();

  const int dt = tid >> 6;
  const int l  = tid & 63;
  const int lm = l & 15;
  const int lg = l >> 4;
  #pragma unroll
  for (int ks2 = 0; ks2 < 2; ++ks2) {
    bf16x8 o;
    #pragma unroll
    for (int jj = 0; jj < 4; ++jj) {
      o[jj]     = (__bf16)tile[ks2 * 32 + lg * 4 + jj][dt * 16 + lm];
      o[jj + 4] = (__bf16)tile[ks2 * 32 + 16 + lg * 4 + jj][dt * 16 + lm];
    }
    *reinterpret_cast<uint4*>(
        Vtile + (size_t)b * VT_B + (size_t)((t0 >> 5) + ks2) * VT_K +
        dt * 512 + l * 8) = __builtin_bit_cast(uint4, o);
  }
}

// ---------------------------------------------------------------------------
// Kernel 3 (R16): R14's proven low-register cooperative structure
// (256 threads = 4 waves, KCH=2 -> 512 blocks = 2 blocks/CU for barrier
// overlap) + R15's proven tiled Qs layout (kills the 2.56M 8-way bank
// conflicts of the XOR-swizzled row-major Qs) + R13's proven bf16 partials
// (halves split traffic). Per 128-k round: S-phase wave w computes its 32-k
// strip for all heads (softmax lane-local, op-diet) -> Ws[w] in B-frag
// layout; PV-phase wave w owns d-quadrant w for all heads (accO = 32 regs).
// ---------------------------------------------------------------------------
template <int KCH>   // 1 = no split (direct fp32 out), 2 = half split
__global__ __launch_bounds__(256, 2) void attn_kernel(
    const float* __restrict__ Q,
    const __hip_bfloat16* __restrict__ Kt,
    const __hip_bfloat16* __restrict__ Vtile,
    float* __restrict__ Out,
    __hip_bfloat16* __restrict__ Pp) {
  const int bx = blockIdx.x;
  int b, q0, c;
  if (KCH == 2) {     // 512 blocks: XCD x gets logical [x*64, x*64+64)
    const int L = (bx & 7) * 64 + (bx >> 3);
    b = L >> 8; const int rest = L & 255; q0 = (rest >> 1) << 4; c = rest & 1;
  } else {            // 256 blocks
    const int L = (bx & 7) * 32 + (bx >> 3);
    b = L >> 7; q0 = (L & 127) << 4; c = 0;
  }
  const int tid = threadIdx.x;
  const int w  = tid >> 6;            // 0..3
  const int l  = tid & 63;
  const int lm = l & 15;
  const int lg = l >> 4;

  constexpr int NRND = KCH == 2 ? 8 : 16;   // 128-k rounds
  const int tsbase = c * 64;                // tset base (16-k units)
  const int kvbase = c * 32;                // kset32 base

  __shared__ __bf16 Qs[8192];               // tiled [hg(16)][lane(64)][8], 16K
  __shared__ __bf16 Ws[4][NHEAD][512];      // 32 KiB, B-frag layout
  __shared__ float  Obuf[64][17];           // 4.4 KiB epilogue transpose

  // ---- stage Q to LDS in tiled layout (pre-scaled by dh^-0.5*log2e) ----
  // Region hg = h*2+g holds lane ll -> row=ll&15, d = g*32 + (ll>>4)*8 + j.
  const float cl2 = 0.125f * 1.44269504f;
  {
    const int hg = tid >> 4;          // 0..15
    const int wi = tid & 15;
    const int h = hg >> 1, g = hg & 1;
    #pragma unroll
    for (int u = 0; u < 4; ++u) {
      const int ll = u * 16 + wi;     // dest lane 0..63 (row=wi, seg=u)
      const float* src = Q + ((size_t)(b * TSEQ + q0 + wi)) * DMODEL +
                         h * DHEAD + g * 32 + u * 8;
      *(bf16x8*)((char*)Qs + hg * 1024 + ll * 16) = cvt8s(src, cl2);
    }
  }
  __syncthreads();

  f32x4 accO[NHEAD];    // [h]: q = lm, d = w*16 + lg*4 + r  (32 regs)
  #pragma unroll
  for (int h = 0; h < NHEAD; ++h) accO[h] = (f32x4){0.f, 0.f, 0.f, 0.f};

  bf16x8 vA[4], vB[4];                 // V per-round double buffer (dt=w)

  #define S_HALF(TSET, S2)                                                    \
    {                                                                         \
      const __hip_bfloat16* kb_ =                                             \
          Kt + (size_t)b * KT_B + (size_t)(TSET) * KT_T + l * 8;              \
      bf16x8 kf0[NHEAD], kf1[NHEAD];                                          \
      _Pragma("unroll")                                                       \
      for (int h = 0; h < NHEAD; ++h) {                                       \
        kf0[h] = load_b8(kb_ + h * 1024);                                     \
        kf1[h] = load_b8(kb_ + h * 1024 + 512);                               \
      }                                                                       \
      f32x4 sv[NHEAD];                                                        \
      __builtin_amdgcn_s_setprio(1);                                          \
      _Pragma("unroll")                                                       \
      for (int h = 0; h < NHEAD; ++h) {                                       \
        bf16x8 q0_ = *(const bf16x8*)((const char*)Qs + (h * 2) * 1024 + l * 16);     \
        bf16x8 q1_ = *(const bf16x8*)((const char*)Qs + (h * 2 + 1) * 1024 + l * 16); \
        f32x4 t = {0.f, 0.f, 0.f, 0.f};                                       \
        t = __builtin_amdgcn_mfma_f32_16x16x32_bf16(kf0[h], q0_, t, 0, 0, 0); \
        t = __builtin_amdgcn_mfma_f32_16x16x32_bf16(kf1[h], q1_, t, 0, 0, 0); \
        sv[h] = t;                                                            \
      }                                                                       \
      __builtin_amdgcn_s_setprio(0);                                          \
      _Pragma("unroll")                                                       \
      for (int rp = 0; rp < 2; ++rp) {                                        \
        float w0_[NHEAD], w1_[NHEAD];                                         \
        float s0_ = 0.f, s1_ = 0.f;                                           \
        _Pragma("unroll")                                                     \
        for (int h = 0; h < NHEAD; ++h) { w0_[h] = EXP2(sv[h][2 * rp]);     s0_ += w0_[h]; } \
        _Pragma("unroll")                                                     \
        for (int h = 0; h < NHEAD; ++h) { w1_[h] = EXP2(sv[h][2 * rp + 1]); s1_ += w1_[h]; } \
        const float i0_ = __builtin_amdgcn_rcpf(s0_);                         \
        const float i1_ = __builtin_amdgcn_rcpf(s1_);                         \
        _Pragma("unroll")                                                     \
        for (int h = 0; h < NHEAD; ++h)                                       \
          wfu[h][(S2) * 2 + rp] = packbf(w0_[h] * i0_, w1_[h] * i1_);         \
      }                                                                       \
    }

  #define ROUND(R, VCUR, VNXT)                                                \
    {                                                                         \
      uint wfu[NHEAD][4];                                                     \
      const int ts0 = tsbase + (R) * 8 + w * 2;                               \
      S_HALF(ts0, 0);                                                         \
      S_HALF(ts0 + 1, 1);                                                     \
      _Pragma("unroll")                                                       \
      for (int h = 0; h < NHEAD; ++h)                                         \
        *reinterpret_cast<uint4*>((char*)(&Ws[w][h][0]) + l * 16) =           \
            uint4{wfu[h][0], wfu[h][1], wfu[h][2], wfu[h][3]};                \
      {                                                                       \
        const int RN = (R) < NRND - 1 ? (R) + 1 : NRND - 1;                   \
        const __hip_bfloat16* vb_ = Vtile + (size_t)b * VT_B +                \
            (size_t)(kvbase + RN * 4) * VT_K + w * 512 + l * 8;               \
        _Pragma("unroll")                                                     \
        for (int s = 0; s < 4; ++s) VNXT[s] = load_b8(vb_ + s * 2048);        \
      }                                                                       \
      __syncthreads();                                                        \
      __builtin_amdgcn_s_setprio(1);                                          \
      _Pragma("unroll")                                                       \
      for (int s = 0; s < 4; ++s) {                                           \
        _Pragma("unroll")                                                     \
        for (int h = 0; h < NHEAD; ++h) {                                     \
          bf16x8 wsf = *(const bf16x8*)((const char*)(&Ws[s][h][0]) + l * 16);\
          accO[h] = __builtin_amdgcn_mfma_f32_16x16x32_bf16(VCUR[s], wsf, accO[h], 0, 0, 0); \
        }                                                                     \
      }                                                                       \
      __builtin_amdgcn_s_setprio(0);                                          \
      __syncthreads();                                                        \
    }

  // prologue: V for round 0
  {
    const __hip_bfloat16* vb_ = Vtile + (size_t)b * VT_B +
        (size_t)kvbase * VT_K + w * 512 + l * 8;
    #pragma unroll
    for (int s = 0; s < 4; ++s) vA[s] = load_b8(vb_ + s * 2048);
  }

  #pragma unroll 1
  for (int rp2 = 0; rp2 < NRND / 2; ++rp2) {
    ROUND(2 * rp2,     vA, vB);
    ROUND(2 * rp2 + 1, vB, vA);
  }

  #undef ROUND
  #undef S_HALF

  // ---- epilogue: per head, LDS transpose then coalesced store ----
  __hip_bfloat16* pbase = Pp +
      ((size_t)((b * 128 + (q0 >> 4)) * 2 + c)) * 8192;
  float* obase = Out + ((size_t)(b * TSEQ + q0)) * DMODEL;
  #pragma unroll
  for (int h = 0; h < NHEAD; ++h) {
    #pragma unroll
    for (int r = 0; r < 4; ++r)
      Obuf[w * 16 + lg * 4 + r][lm] = accO[h][r];
    __syncthreads();
    {
      const int q  = tid >> 4;         // 0..15
      const int d0 = (tid & 15) * 4;   // within-head d, 0..60
      float4 s = {Obuf[d0][q], Obuf[d0 + 1][q], Obuf[d0 + 2][q], Obuf[d0 + 3][q]};
      if (KCH == 2) {
        bf16x4 pb;
        pb[0] = (__bf16)s.x; pb[1] = (__bf16)s.y;
        pb[2] = (__bf16)s.z; pb[3] = (__bf16)s.w;
        *reinterpret_cast<uint2*>(&pbase[(size_t)q * 512 + h * DHEAD + d0]) =
            __builtin_bit_cast(uint2, pb);
      } else {
        *reinterpret_cast<float4*>(&obase[(size_t)q * 512 + h * DHEAD + d0]) = s;
      }
    }
    __syncthreads();
  }
}

// ---------------------------------------------------------------------------
// Kernel 4 (split mode): Out = sum of 2 bf16 partial chunks.
// 1024 blocks x 256 threads; each thread produces 8 contiguous outputs.
// ---------------------------------------------------------------------------
__global__ void reduce_kernel(const __hip_bfloat16* __restrict__ Pp,
                              float* __restrict__ Out) {
  const int g  = blockIdx.x * 256 + threadIdx.x;   // 0..262143
  const int f0 = g << 3;
  const int d0 = f0 & 511;
  const int q  = (f0 >> 9) & 2047;
  const int b  = f0 >> 20;
  const __hip_bfloat16* p = Pp +
      ((size_t)(b * 128 + (q >> 4)) * 2) * 8192 + (size_t)(q & 15) * 512 + d0;
  float acc[8] = {0.f, 0.f, 0.f, 0.f, 0.f, 0.f, 0.f, 0.f};
  #pragma unroll
  for (int c = 0; c < 2; ++c) {
    uint4 u = *reinterpret_cast<const uint4*>(p + c * 8192);
    const uint uu[4] = {u.x, u.y, u.z, u.w};
    #pragma unroll
    for (int j = 0; j < 4; ++j) {
      acc[2 * j]     += __builtin_bit_cast(float, uu[j] << 16);
      acc[2 * j + 1] += __builtin_bit_cast(float, uu[j] & 0xFFFF0000u);
    }
  }
  float4* o = reinterpret_cast<float4*>(Out + f0);
  o[0] = float4{acc[0], acc[1], acc[2], acc[3]};
  o[1] = float4{acc[4], acc[5], acc[6], acc[7]};
}

// ---------------------------------------------------------------------------
extern "C" void kernel_launch(void* const* d_in, const int* in_sizes, int n_in,
                              void* d_out, int out_size, void* d_ws, size_t ws_size,
                              hipStream_t stream) {
  const float* Q    = (const float*)d_in[0];
  const float* V    = (const float*)d_in[1];
  const float* W    = (const float*)d_in[2];
  const float* bias = (const float*)d_in[3];
  float* Out = (float*)d_out;

  // ws layout: Kt bf16 4MiB | Vtile bf16 512KiB | Pp bf16 8MiB (split only)
  __hip_bfloat16* Ktb = (__hip_bfloat16*)d_ws;
  __hip_bfloat16* Vtb = Ktb + (size_t)BATCH * KT_B;
  const size_t pOff = 4u * 1024 * 1024 + 512u * 1024;
  __hip_bfloat16* Pp = (__hip_bfloat16*)((char*)d_ws + pOff);
  const bool split = ws_size >= pOff + (size_t)2 * BATCH * TSEQ * DMODEL * 2;

  conv_kernel<<<256, 256, 0, stream>>>(V, W, bias, Ktb);
  vt_kernel<<<64, 256, 0, stream>>>(V, Vtb);
  if (split) {
    attn_kernel<2><<<512, 256, 0, stream>>>(Q, Ktb, Vtb, Out, Pp);
    reduce_kernel<<<1024, 256, 0, stream>>>(Pp, Out);
  } else {
    attn_kernel<1><<<256, 256, 0, stream>>>(Q, Ktb, Vtb, Out, Pp);
  }
}